// Round 17
// baseline (272.290 us; speedup 1.0000x reference)
//
#include <hip/hip_runtime.h>
#include <hip/hip_bf16.h>
#include <hip/hip_fp16.h>

typedef _Float16 f16;
typedef _Float16 f16x8 __attribute__((ext_vector_type(8)));
typedef float f32x4 __attribute__((ext_vector_type(4)));
typedef float f32x16 __attribute__((ext_vector_type(16)));

#define SP 16384             // 128*128 spatial per batch
#define NPAIRS 2048          // 32-spatial pairs (4 batches * 512)
#define XF_BYTES ((size_t)NPAIRS * 81920)
#define PPB 8                // pairs per persistent block (256*8 = 2048)

// Counted-waitcnt barriers (T4): __syncthreads would drain vmcnt(0) and
// kill cross-pair staging overlap.
#define BAR_VM(N)                                                    \
  do {                                                               \
    asm volatile("s_waitcnt vmcnt(" #N ")" ::: "memory");            \
    __builtin_amdgcn_s_barrier();                                    \
    __builtin_amdgcn_sched_barrier(0);                               \
  } while (0)
#define BAR_LGKM()                                                   \
  do {                                                               \
    asm volatile("s_waitcnt lgkmcnt(0)" ::: "memory");               \
    __builtin_amdgcn_s_barrier();                                    \
    __builtin_amdgcn_sched_barrier(0);                               \
  } while (0)

// xf PAIR layout (80 KB per 32-spatial pair, 32x32x16-B-fragment-ready):
//   f16 idx = pair*40960 + t*8192 + ks*512 + lane*8 + e
//   holds x[t, d = ks*16 + (lane>>5)*8 + e, s = pair*32 + (lane&31)]
// weight fragment layout (A-operand, m=32 = head-pair):
//   wf f16 idx = ((mat*8 + hp)*16 + ks)*512 + lane*8 + e
//   holds W^T[hp*32 + (lane&31)][ks*16 + (lane>>5)*8 + e]
// as_ layout (16 KB, proj-A-fragment): byte(feat,s) =
//   (feat>>4)*1024 + (((feat&15)>>3)*32 + s)*16 + (feat&7)*2

__global__ __launch_bounds__(512) void prep_frag(const float* __restrict__ Wq,
                                                 const float* __restrict__ Wkv,
                                                 const float* __restrict__ Wp,
                                                 f16* __restrict__ wf) {
  const int gid = blockIdx.x * 512 + threadIdx.x;  // 0..32767
  const int mat = gid >> 13;
  const int rem = gid & 8191;
  const int hp = rem >> 10;         // head-pair 0..7
  const int ks = (rem >> 6) & 15;
  const int lane = rem & 63;
  const int f = hp * 32 + (lane & 31);
  const int kb = ks * 16 + (lane >> 5) * 8;
  f16x8 pk;
#pragma unroll
  for (int e = 0; e < 8; ++e) {
    float v;
    if (mat == 0)      v = Wq[(kb + e) * 256 + f];
    else if (mat == 1) v = Wkv[(kb + e) * 512 + f];
    else if (mat == 2) v = Wkv[(kb + e) * 512 + 256 + f];
    else               v = Wp[(kb + e) * 256 + f];
    pk[e] = (f16)v;
  }
  *(f16x8*)(wf + (size_t)gid * 8) = pk;
}

// Kernel A: transpose/cast x -> xf (pair-fragment layout), full input.
__global__ __launch_bounds__(256) void xpose(const float* __restrict__ x,
                                             f16* __restrict__ xf) {
  __shared__ float ls[32 * 258];
  const int blk = blockIdx.x;
  const int sg = blk & 63;          // 256-s chunk
  const int k0 = (blk >> 6) & 7;    // 32-d chunk
  const int t  = (blk >> 9) % 5;
  const int bl = blk / 2560;        // batch 0..3
  const int tid = threadIdx.x;

  const float* xA = x + ((size_t)((bl * 5 + t) * 256 + k0 * 32)) * SP + sg * 256;
#pragma unroll
  for (int j = 0; j < 8; ++j) {
    const int qq = j * 256 + tid;
    const int dl = qq >> 6, s4 = qq & 63;
    const f32x4 v = *(const f32x4*)(xA + (size_t)dl * SP + s4 * 4);
    *(f32x4*)&ls[dl * 258 + s4 * 4] = v;
  }
  __syncthreads();

#pragma unroll
  for (int pp = 0; pp < 4; ++pp) {
    const int q = pp * 256 + tid;     // 1024 pieces of 16 B
    const int pl  = q >> 7;           // pair-local 0..7
    const int ksl = (q >> 6) & 1;     // ks within this 32-d chunk
    const int l   = q & 63;
    const int hi = l >> 5, sc = l & 31;
    f16x8 pk;
#pragma unroll
    for (int e = 0; e < 8; ++e)
      pk[e] = (f16)ls[(ksl * 16 + hi * 8 + e) * 258 + pl * 32 + sc];
    const int pair = bl * 512 + sg * 8 + pl;
    f16* dst = xf + (size_t)pair * 40960 + t * 8192 + (k0 * 2 + ksl) * 512
                  + l * 8;
    *(f16x8*)dst = pk;
  }
}

// Kernel B: persistent, 1 block/CU, 32x32x16 MFMA (m=2 heads, n=pair),
// counted-vmcnt double-buffered pair staging. Wave = head-pair w.
__global__ __launch_bounds__(512, 2) void fused(
    const f16* __restrict__ xf,
    const float* __restrict__ bq,
    const float* __restrict__ bkv,
    const float* __restrict__ bp,
    const float* __restrict__ pos_bias,
    const f16* __restrict__ wf,
    float* __restrict__ out) {
  __shared__ __align__(16) char lds[163840];  // X0=[0,80K), X1=[80K,160K)

  const int tid = threadIdx.x;
  const int lane = tid & 63;
  const int w = tid >> 6;        // wave = head-pair (heads 2w, 2w+1)
  const int scol = lane & 31;    // spatial within pair
  const int hi = lane >> 5;
  const int hA = 2 * w;

  const f16* wqb = wf + (size_t)(0 * 8 + w) * 8192 + lane * 8;
  const f16* wkb = wf + (size_t)(1 * 8 + w) * 8192 + lane * 8;
  const f16* wvb = wf + (size_t)(2 * 8 + w) * 8192 + lane * 8;
  const f16* wpb = wf + (size_t)(3 * 8 + w) * 8192 + lane * 8;

  const int pair0 = blockIdx.x * PPB;

  // stage pair p (80 KB contiguous) into buffer buf: 10 glls/wave
  auto stage_pair = [&](int p, int buf) {
    const char* src = (const char*)xf + (size_t)p * 81920 + w * 10240 + lane * 16;
    char* dst = lds + buf * 81920 + w * 10240 + lane * 16;
#pragma unroll
    for (int n = 0; n < 10; ++n)
      __builtin_amdgcn_global_load_lds(
          (const void __attribute__((address_space(1)))*)(src + n * 1024),
          (void __attribute__((address_space(3)))*)(dst + n * 1024), 16, 0, 0);
  };

  stage_pair(pair0, 0);
  BAR_VM(0);  // prologue: X0 visible

  for (int i = 0; i < PPB; ++i) {
    const int buf = i & 1;
    char* Xb = lds + buf * 81920;

    if (i > 0) BAR_VM(4);  // drain stage(i); leave 4 newest (prev stores)

    if (i + 1 < PPB) stage_pair(pair0 + i + 1, buf ^ 1);

    // ---- q/k/v GEMM: C[m=2 heads x 16 dk][n=32 s], K=256 in 16 steps ----
    f32x16 qacc = {};
    f32x16 kacc[5] = {};
    f32x16 vacc[5] = {};
    __builtin_amdgcn_s_setprio(1);
#pragma unroll 1
    for (int ks = 0; ks < 16; ++ks) {
      const f16x8 fq = *(const f16x8*)(wqb + ks * 512);
      const f16x8 fk = *(const f16x8*)(wkb + ks * 512);
      const f16x8 fv = *(const f16x8*)(wvb + ks * 512);
      const int xb = ks * 1024 + lane * 16;
      f16x8 xt[5];
#pragma unroll
      for (int t = 0; t < 5; ++t)
        xt[t] = *(const f16x8*)(Xb + t * 16384 + xb);
      qacc = __builtin_amdgcn_mfma_f32_32x32x16_f16(fq, xt[0], qacc, 0, 0, 0);
#pragma unroll
      for (int t = 0; t < 5; ++t) {
        kacc[t] = __builtin_amdgcn_mfma_f32_32x32x16_f16(fk, xt[t], kacc[t], 0, 0, 0);
        vacc[t] = __builtin_amdgcn_mfma_f32_32x32x16_f16(fv, xt[t], vacc[t], 0, 0, 0);
      }
    }
    __builtin_amdgcn_s_setprio(0);

    // ---- attention: lane holds 8 dk/head (rows m) for one s (=scol) ----
    // m(reg rl) = (rl&3) + 8*(rl>>2) + 4*hi; head j uses regs j*8..j*8+7
    unsigned long long pko[2][2];  // [j][half] packed f16x4 outputs
#pragma unroll
    for (int j = 0; j < 2; ++j) {
      const int hj = hA + j;
      float pb[5], bqr[8], bkr[8], bvr[8];
#pragma unroll
      for (int t = 0; t < 5; ++t) pb[t] = pos_bias[hj * 5 + t];
#pragma unroll
      for (int rl = 0; rl < 8; ++rl) {
        const int dk = (rl & 3) + 8 * (rl >> 2) + 4 * hi;
        bqr[rl] = bq[hj * 16 + dk];
        bkr[rl] = bkv[hj * 16 + dk];
        bvr[rl] = bkv[256 + hj * 16 + dk];
      }
      float qv[8];
#pragma unroll
      for (int rl = 0; rl < 8; ++rl) qv[rl] = qacc[j * 8 + rl] + bqr[rl];
      float sc[5];
#pragma unroll
      for (int t = 0; t < 5; ++t) {
        float p = 0.f;
#pragma unroll
        for (int rl = 0; rl < 8; ++rl)
          p += qv[rl] * (kacc[t][j * 8 + rl] + bkr[rl]);
        p += __shfl_xor(p, 32);  // partner lane holds the other 8 dk
        sc[t] = p * 4.0f + pb[t];  // /temperature (=0.25) + pos_bias
      }
      float m = sc[0];
#pragma unroll
      for (int t = 1; t < 5; ++t) m = fmaxf(m, sc[t]);
      float l = 0.f;
#pragma unroll
      for (int t = 0; t < 5; ++t) { sc[t] = __expf(sc[t] - m); l += sc[t]; }
      const float inv = 1.0f / l;
      float o8[8];
#pragma unroll
      for (int rl = 0; rl < 8; ++rl) {
        float o = 0.f;
#pragma unroll
        for (int t = 0; t < 5; ++t) o += sc[t] * vacc[t][j * 8 + rl];
        o8[rl] = o * inv + bvr[rl];
      }
      union { f16 h[4]; unsigned long long u; } p1, p2;
#pragma unroll
      for (int r4 = 0; r4 < 4; ++r4) {
        p1.h[r4] = (f16)o8[r4];       // dk = r4 + 4hi      (feat&15 < 8)
        p2.h[r4] = (f16)o8[4 + r4];   // dk = 8 + r4 + 4hi  (feat&15 >= 8)
      }
      pko[j][0] = p1.u;
      pko[j][1] = p2.u;
    }

    BAR_LGKM();  // bar_A: all x LDS reads done; stage glls stay in flight

    // ---- write as_ overlay (first 16 KB of Xb) ----
#pragma unroll
    for (int j = 0; j < 2; ++j) {
      const int ksq = w * 2 + j;
      *(unsigned long long*)(Xb + ksq * 1024 + scol * 16 + hi * 8) = pko[j][0];
      *(unsigned long long*)(Xb + ksq * 1024 + (scol + 32) * 16 + hi * 8) = pko[j][1];
    }
    BAR_LGKM();  // bar_B: as_ visible; stage glls still in flight

    // ---- projection: C[m=32 s][n=32 douts], A=as_, B=Wp ----
    f32x16 facc = {};
    __builtin_amdgcn_s_setprio(1);
#pragma unroll 1
    for (int ks = 0; ks < 16; ++ks) {
      const f16x8 af = *(const f16x8*)(Xb + ks * 1024 + lane * 16);
      const f16x8 fp = *(const f16x8*)(wpb + ks * 512);
      facc = __builtin_amdgcn_mfma_f32_32x32x16_f16(af, fp, facc, 0, 0, 0);
    }
    __builtin_amdgcn_s_setprio(0);

    // ---- store: lane owns dout dg for 16 s rows (4 x f32x4) ----
    {
      const int p = pair0 + i;
      const int b = p >> 9, s0 = (p & 511) << 5;
      const int dg = w * 32 + scol;
      const float bias = bp[dg];
      float* obase = out + ((size_t)b * 256 + dg) * SP + s0 + 4 * hi;
#pragma unroll
      for (int g = 0; g < 4; ++g) {
        f32x4 vs;
#pragma unroll
        for (int rr = 0; rr < 4; ++rr) vs[rr] = facc[4 * g + rr] + bias;
        *(f32x4*)(obase + 8 * g) = vs;
      }
    }
    // no bar_C: next write to Xb is stage(i+2), behind next pair-top barrier
  }
}

extern "C" void kernel_launch(void* const* d_in, const int* in_sizes, int n_in,
                              void* d_out, int out_size, void* d_ws, size_t ws_size,
                              hipStream_t stream) {
  const float* x   = (const float*)d_in[0];
  const float* Wq  = (const float*)d_in[1];
  const float* bq  = (const float*)d_in[2];
  const float* Wkv = (const float*)d_in[3];
  const float* bkv = (const float*)d_in[4];
  const float* Wp  = (const float*)d_in[5];
  const float* bp  = (const float*)d_in[6];
  const float* pos = (const float*)d_in[7];

  f16* xf = (f16*)d_ws;                        // 168 MB
  f16* wf = (f16*)((char*)d_ws + XF_BYTES);    // 512 KB fragment weights

  prep_frag<<<64, 512, 0, stream>>>(Wq, Wkv, Wp, wf);
  xpose<<<10240, 256, 0, stream>>>(x, xf);
  fused<<<256, 512, 0, stream>>>(xf, bq, bkv, bp, pos, wf, (float*)d_out);
}

// Round 18
// 234.628 us; speedup vs baseline: 1.1605x; 1.1605x over previous
//
#include <hip/hip_runtime.h>
#include <hip/hip_bf16.h>
#include <hip/hip_fp16.h>

typedef _Float16 f16;
typedef _Float16 f16x8 __attribute__((ext_vector_type(8)));
typedef float f32x4 __attribute__((ext_vector_type(4)));

#define SP 16384             // 128*128 spatial per batch
#define NTILES 4096
#define XF_BYTES ((size_t)NTILES * 40960)
#define PPB 8                // tile-pairs per persistent block (256*8*2 = 4096)

// Counted-waitcnt barriers (T4): __syncthreads would drain vmcnt(0) and
// kill cross-pair staging overlap.
#define BAR_VM(N)                                                    \
  do {                                                               \
    asm volatile("s_waitcnt vmcnt(" #N ")" ::: "memory");            \
    __builtin_amdgcn_s_barrier();                                    \
    __builtin_amdgcn_sched_barrier(0);                               \
  } while (0)
#define BAR_LGKM()                                                   \
  do {                                                               \
    asm volatile("s_waitcnt lgkmcnt(0)" ::: "memory");               \
    __builtin_amdgcn_s_barrier();                                    \
    __builtin_amdgcn_sched_barrier(0);                               \
  } while (0)
// Bare barrier: per-wave LDS reads are already complete by data dependency
// (their values fed MFMAs); only cross-wave ordering is needed.
#define BAR_ONLY()                                                   \
  do {                                                               \
    __builtin_amdgcn_s_barrier();                                    \
    __builtin_amdgcn_sched_barrier(0);                               \
  } while (0)

// xf tile layout (40 KB per 16-spatial tile, LANE-LINEAR fragments):
//   byte = t*8192 + k0*1024 + g4*256 + c*16 + e*2 = x[t, d=k0*32+g4*8+e, s=16*tile+c]
// weight fragment layout (lane-linear, 1 KB per (mat,head,k0)):
//   wf f16 idx = ((mat*16+h)*8 + k0)*512 + lane*8 + e

__global__ __launch_bounds__(512) void prep_frag(const float* __restrict__ Wq,
                                                 const float* __restrict__ Wkv,
                                                 const float* __restrict__ Wp,
                                                 f16* __restrict__ wf) {
  const int gid = blockIdx.x * 512 + threadIdx.x;  // 0..32767
  const int mat = gid >> 13;
  const int rem = gid & 8191;
  const int h = rem >> 9;
  const int k0 = (rem >> 6) & 7;
  const int lane = rem & 63;
  const int c = lane & 15, g4 = lane >> 4;
  const int fr = h * 16 + c;
  const int kb = k0 * 32 + g4 * 8;
  f16x8 pk;
#pragma unroll
  for (int e = 0; e < 8; ++e) {
    float v;
    if (mat == 0)      v = Wq[(kb + e) * 256 + fr];
    else if (mat == 1) v = Wkv[(kb + e) * 512 + fr];
    else if (mat == 2) v = Wkv[(kb + e) * 512 + 256 + fr];
    else               v = Wp[(kb + e) * 256 + fr];
    pk[e] = (f16)v;
  }
  *(f16x8*)(wf + (size_t)gid * 8) = pk;
}

// Kernel A: transpose/cast x -> xf (fragment layout), full input.
__global__ __launch_bounds__(256) void xpose(const float* __restrict__ x,
                                             f16* __restrict__ xf) {
  __shared__ float ls[32 * 258];
  const int blk = blockIdx.x;
  const int sg = blk & 63;
  const int k0 = (blk >> 6) & 7;
  const int t  = (blk >> 9) % 5;
  const int bl = blk / 2560;
  const int tid = threadIdx.x;

  const float* xA = x + ((size_t)((bl * 5 + t) * 256 + k0 * 32)) * SP + sg * 256;
#pragma unroll
  for (int j = 0; j < 8; ++j) {
    const int qq = j * 256 + tid;
    const int dl = qq >> 6, s4 = qq & 63;
    const f32x4 v = *(const f32x4*)(xA + (size_t)dl * SP + s4 * 4);
    *(f32x4*)&ls[dl * 258 + s4 * 4] = v;
  }
  __syncthreads();

  const int tile_base = bl * 1024 + sg * 16;
#pragma unroll
  for (int pp = 0; pp < 4; ++pp) {
    const int piece = pp * 256 + tid;
    const int tt = piece >> 6;
    const int c  = (piece >> 2) & 15;
    const int g4 = piece & 3;
    f16x8 pk;
#pragma unroll
    for (int e = 0; e < 8; ++e)
      pk[e] = (f16)ls[(g4 * 8 + e) * 258 + tt * 16 + c];
    f16* dst = xf + (size_t)(tile_base + tt) * 20480 + t * 4096 + k0 * 512
                  + g4 * 128 + c * 8;
    *(f16x8*)dst = pk;
  }
}

// Kernel B: persistent, 1 block/CU, U=2, single-pass qkv, counted-vmcnt
// double-buffered pair staging. k-loops at unroll 2 (R17 proved the register
// budget at 2 waves/SIMD is ~300+, not 256 -> compiler can software-pipeline
// iteration k0+1's L2 loads under k0's MFMAs).
__global__ __launch_bounds__(512, 2) void fused(
    const f16* __restrict__ xf,
    const float* __restrict__ bq,
    const float* __restrict__ bkv,
    const float* __restrict__ bp,
    const float* __restrict__ pos_bias,
    const f16* __restrict__ wf,
    float* __restrict__ out) {
  __shared__ __align__(16) char lds[163840];  // X0=[0,80K), X1=[80K,160K)

  const int tid = threadIdx.x;
  const int lane = tid & 63;
  const int w = tid >> 6;    // wave 0..7 -> heads 2w, 2w+1
  const int c = lane & 15;
  const int g4 = lane >> 4;
  const int hA = 2 * w;

  const f16* wfq = wf;
  const f16* wfk = wf + 65536;
  const f16* wfv = wf + 131072;
  const f16* wfp = wf + 196608;

  const int pair0 = blockIdx.x * PPB;

  // stage pair p (80 KB contiguous in xf) into buffer buf: 10 glls/wave
  auto stage_pair = [&](int p, int buf) {
    const char* src = (const char*)xf + (size_t)p * 81920 + w * 5120 + lane * 16;
    char* dst = lds + buf * 81920 + w * 5120 + lane * 16;
#pragma unroll
    for (int u = 0; u < 2; ++u)
#pragma unroll
      for (int n = 0; n < 5; ++n)
        __builtin_amdgcn_global_load_lds(
            (const void __attribute__((address_space(1)))*)(src + u * 40960 + n * 1024),
            (void __attribute__((address_space(3)))*)(dst + u * 40960 + n * 1024),
            16, 0, 0);
  };

  stage_pair(pair0, 0);
  BAR_VM(0);  // prologue: X0 fully visible

  for (int i = 0; i < PPB; ++i) {
    const int buf = i & 1;
    char* Xb = lds + buf * 81920;

    if (i > 0) BAR_VM(4);  // drain stage(i); leave 4 newest (prev stores)

    // issue next pair's staging; drains only at NEXT pair-top vmcnt(4)
    if (i + 1 < PPB) stage_pair(pair0 + i + 1, buf ^ 1);

    // ---- single-pass q/k/v GEMM, both tiles (C[m=dk][n=s]) ----
    f32x4 qacc[2][2] = {};      // [tile][head]
    f32x4 kacc[2][2][5] = {};
    f32x4 vacc[2][2][5] = {};
#pragma unroll 2
    for (int k0 = 0; k0 < 8; ++k0) {
      const int wb = k0 * 512 + lane * 8;
      const f16x8 fq0 = *(const f16x8*)(wfq + hA * 4096 + wb);
      const f16x8 fq1 = *(const f16x8*)(wfq + (hA + 1) * 4096 + wb);
      const f16x8 fk0 = *(const f16x8*)(wfk + hA * 4096 + wb);
      const f16x8 fk1 = *(const f16x8*)(wfk + (hA + 1) * 4096 + wb);
      const f16x8 fv0 = *(const f16x8*)(wfv + hA * 4096 + wb);
      const f16x8 fv1 = *(const f16x8*)(wfv + (hA + 1) * 4096 + wb);
      const int base = (k0 << 10) + (g4 << 8) + (c << 4);
#pragma unroll
      for (int u = 0; u < 2; ++u) {
        const char* fbp = Xb + u * 40960;
        f16x8 xfr[5];
#pragma unroll
        for (int t = 0; t < 5; ++t) xfr[t] = *(const f16x8*)(fbp + (t << 13) + base);
        qacc[u][0] = __builtin_amdgcn_mfma_f32_16x16x32_f16(fq0, xfr[0], qacc[u][0], 0, 0, 0);
        qacc[u][1] = __builtin_amdgcn_mfma_f32_16x16x32_f16(fq1, xfr[0], qacc[u][1], 0, 0, 0);
#pragma unroll
        for (int t = 0; t < 5; ++t) {
          kacc[u][0][t] = __builtin_amdgcn_mfma_f32_16x16x32_f16(fk0, xfr[t], kacc[u][0][t], 0, 0, 0);
          kacc[u][1][t] = __builtin_amdgcn_mfma_f32_16x16x32_f16(fk1, xfr[t], kacc[u][1][t], 0, 0, 0);
          vacc[u][0][t] = __builtin_amdgcn_mfma_f32_16x16x32_f16(fv0, xfr[t], vacc[u][0][t], 0, 0, 0);
          vacc[u][1][t] = __builtin_amdgcn_mfma_f32_16x16x32_f16(fv1, xfr[t], vacc[u][1][t], 0, 0, 0);
        }
      }
    }

    // ---- attention, fully in-register ----
    f32x4 o[2][2];
#pragma unroll
    for (int j = 0; j < 2; ++j) {
      const int hj = hA + j;
      float bqr[4], bkr[4], bvr[4], pb[5];
#pragma unroll
      for (int t = 0; t < 5; ++t) pb[t] = pos_bias[hj * 5 + t];
#pragma unroll
      for (int rr = 0; rr < 4; ++rr) {
        bqr[rr] = bq[hj * 16 + 4 * g4 + rr];
        bkr[rr] = bkv[hj * 16 + 4 * g4 + rr];
        bvr[rr] = bkv[256 + hj * 16 + 4 * g4 + rr];
      }
#pragma unroll
      for (int u = 0; u < 2; ++u) {
        float qv[4];
#pragma unroll
        for (int rr = 0; rr < 4; ++rr) qv[rr] = qacc[u][j][rr] + bqr[rr];
        float sc[5];
#pragma unroll
        for (int t = 0; t < 5; ++t) {
          float p = 0.f;
#pragma unroll
          for (int rr = 0; rr < 4; ++rr) p += qv[rr] * (kacc[u][j][t][rr] + bkr[rr]);
          p += __shfl_xor(p, 16);
          p += __shfl_xor(p, 32);
          sc[t] = p * 4.0f + pb[t];  // /temperature (=0.25) + pos_bias
        }
        float m = sc[0];
#pragma unroll
        for (int t = 1; t < 5; ++t) m = fmaxf(m, sc[t]);
        float l = 0.f;
#pragma unroll
        for (int t = 0; t < 5; ++t) { sc[t] = __expf(sc[t] - m); l += sc[t]; }
        const float inv = 1.0f / l;
        f32x4 oo = {};
#pragma unroll
        for (int t = 0; t < 5; ++t)
#pragma unroll
          for (int rr = 0; rr < 4; ++rr) oo[rr] += sc[t] * vacc[u][j][t][rr];
#pragma unroll
        for (int rr = 0; rr < 4; ++rr) oo[rr] = oo[rr] * inv + bvr[rr];
        o[u][j] = oo;
      }
    }

    BAR_ONLY();  // bar_A: cross-wave ordering only (per-wave LDS reads are
                 // complete by data dependency); stage glls stay in flight

    // ---- write as_ overlay (first 16 KB of Xb; lane-linear b64) ----
#pragma unroll
    for (int u = 0; u < 2; ++u)
#pragma unroll
      for (int j = 0; j < 2; ++j) {
        union { f16 hh[4]; unsigned long long uu; } pk;
#pragma unroll
        for (int rr = 0; rr < 4; ++rr) pk.hh[rr] = (f16)o[u][j][rr];
        const int byte = (w << 10) + ((2 * j + (g4 >> 1)) << 8) + (c << 4)
                         + ((g4 & 1) << 3);
        *(unsigned long long*)(Xb + u * 8192 + byte) = pk.uu;
      }
    BAR_LGKM();  // bar_B: as_ visible; stage glls still in flight

    // ---- projection ----
    f32x4 facc[2][2] = {};
#pragma unroll 2
    for (int k0 = 0; k0 < 8; ++k0) {
      const int wb = k0 * 512 + lane * 8;
      const f16x8 f0 = *(const f16x8*)(wfp + hA * 4096 + wb);
      const f16x8 f1 = *(const f16x8*)(wfp + (hA + 1) * 4096 + wb);
      const int abyte = (k0 << 10) + (g4 << 8) + (c << 4);
#pragma unroll
      for (int u = 0; u < 2; ++u) {
        const f16x8 af = *(const f16x8*)(Xb + u * 8192 + abyte);
        facc[u][0] = __builtin_amdgcn_mfma_f32_16x16x32_f16(af, f0, facc[u][0], 0, 0, 0);
        facc[u][1] = __builtin_amdgcn_mfma_f32_16x16x32_f16(af, f1, facc[u][1], 0, 0, 0);
      }
    }

    // ---- store (4 f32x4/wave; left pending across next pair-top) ----
#pragma unroll
    for (int u = 0; u < 2; ++u) {
      const int g = (pair0 + i) * 2 + u;
      const int b = g >> 10, s0 = (g & 1023) << 4;
#pragma unroll
      for (int j = 0; j < 2; ++j) {
        const int dg = (hA + j) * 16 + c;
        f32x4 vs = facc[u][j];
        const float bias = bp[dg];
#pragma unroll
        for (int rr = 0; rr < 4; ++rr) vs[rr] += bias;
        float* dst = out + ((size_t)b * 256 + dg) * SP + s0 + (g4 << 2);
        *(f32x4*)dst = vs;
      }
    }
    // no bar_C: next write to Xb is stage(i+2), behind next pair-top barrier
  }
}

extern "C" void kernel_launch(void* const* d_in, const int* in_sizes, int n_in,
                              void* d_out, int out_size, void* d_ws, size_t ws_size,
                              hipStream_t stream) {
  const float* x   = (const float*)d_in[0];
  const float* Wq  = (const float*)d_in[1];
  const float* bq  = (const float*)d_in[2];
  const float* Wkv = (const float*)d_in[3];
  const float* bkv = (const float*)d_in[4];
  const float* Wp  = (const float*)d_in[5];
  const float* bp  = (const float*)d_in[6];
  const float* pos = (const float*)d_in[7];

  f16* xf = (f16*)d_ws;                        // 168 MB
  f16* wf = (f16*)((char*)d_ws + XF_BYTES);    // 512 KB fragment weights

  prep_frag<<<64, 512, 0, stream>>>(Wq, Wkv, Wp, wf);
  xpose<<<10240, 256, 0, stream>>>(x, xf);
  fused<<<256, 512, 0, stream>>>(xf, bq, bkv, bp, pos, wf, (float*)d_out);
}